// Round 14
// baseline (408.828 us; speedup 1.0000x reference)
//
#include <hip/hip_runtime.h>
#include <math.h>

#define N_NODES 20000
#define E_EDGES 320000
#define IN_CH   300
#define HID     100
#define R_REL   50
#define NB      8
#define CLS     3
#define NQ      64
#define OUTW    800   // NB * HID
#define ZW      128   // Z row stride (ushorts): 256-B rows, batched-4 writes
#define SCAN_BLKS ((N_NODES + 255) / 256)   // 79

typedef unsigned short ushort_t;
typedef __attribute__((ext_vector_type(8))) short     short8;
typedef __attribute__((ext_vector_type(8))) unsigned short ushort8;
typedef __attribute__((ext_vector_type(4))) float     f32x4;
typedef __attribute__((ext_vector_type(2))) float     f32x2;

__device__ __forceinline__ ushort_t f2bf_rne(float f) {   // round-nearest-even
    unsigned u = __float_as_uint(f);
    unsigned r = (u + 0x7fffu + ((u >> 16) & 1u)) >> 16;
    return (ushort_t)r;
}
__device__ __forceinline__ float bf2f(ushort_t u) {
    return __uint_as_float((unsigned)u << 16);
}

// ============================ CSR build =================================
__global__ __launch_bounds__(256) void zero_deg2(int* __restrict__ dd,
                                                 int* __restrict__ ds) {
    int i = blockIdx.x * 256 + threadIdx.x;
    if (i < N_NODES) { dd[i] = 0; ds[i] = 0; }
}

__global__ __launch_bounds__(256) void hist2_kernel(
        const int* __restrict__ ei, int* __restrict__ dd,
        int* __restrict__ ds) {
    int e = blockIdx.x * 256 + threadIdx.x;
    if (e < E_EDGES) {
        atomicAdd(&dd[ei[E_EDGES + e]], 1);
        atomicAdd(&ds[ei[e]], 1);
    }
}

// dual-set scans: blockIdx selects (deg_d...) or (deg_s...) set
__global__ __launch_bounds__(256) void scan1_both(
        const int* __restrict__ deg_d, int* __restrict__ rp_d, int* __restrict__ bsum_d,
        const int* __restrict__ deg_s, int* __restrict__ rp_s, int* __restrict__ bsum_s) {
    int set = blockIdx.x / SCAN_BLKS, blk = blockIdx.x % SCAN_BLKS;
    const int* deg = set ? deg_s : deg_d;
    int* rowptr    = set ? rp_s  : rp_d;
    int* bsum      = set ? bsum_s : bsum_d;
    __shared__ int s[256];
    int tid = threadIdx.x;
    int idx = blk * 256 + tid;
    int v = (idx < N_NODES) ? deg[idx] : 0;
    s[tid] = v; __syncthreads();
    #pragma unroll
    for (int off = 1; off < 256; off <<= 1) {
        int t = (tid >= off) ? s[tid - off] : 0;
        __syncthreads();
        s[tid] += t;
        __syncthreads();
    }
    if (idx < N_NODES) rowptr[idx] = s[tid] - v;   // exclusive
    if (tid == 255) bsum[blk] = s[255];
}

__global__ __launch_bounds__(128) void scan2_both(
        int* __restrict__ bsum_d, int* __restrict__ rp_d,
        int* __restrict__ bsum_s, int* __restrict__ rp_s) {
    int* bsum   = blockIdx.x ? bsum_s : bsum_d;
    int* rowptr = blockIdx.x ? rp_s   : rp_d;
    __shared__ int s[128];
    int tid = threadIdx.x;
    int v = (tid < SCAN_BLKS) ? bsum[tid] : 0;
    s[tid] = v; __syncthreads();
    #pragma unroll
    for (int off = 1; off < 128; off <<= 1) {
        int t = (tid >= off) ? s[tid - off] : 0;
        __syncthreads();
        s[tid] += t;
        __syncthreads();
    }
    if (tid < SCAN_BLKS) bsum[tid] = s[tid] - v;   // exclusive
    if (tid == 0) rowptr[N_NODES] = E_EDGES;
}

__global__ __launch_bounds__(256) void scan3_both(
        int* __restrict__ rp_d, const int* __restrict__ bsum_d, int* __restrict__ cur_d,
        int* __restrict__ rp_s, const int* __restrict__ bsum_s, int* __restrict__ cur_s) {
    int set = blockIdx.x / SCAN_BLKS, blk = blockIdx.x % SCAN_BLKS;
    int* rowptr      = set ? rp_s   : rp_d;
    const int* bsum  = set ? bsum_s : bsum_d;
    int* cursor      = set ? cur_s  : cur_d;
    int idx = blk * 256 + threadIdx.x;
    if (idx < N_NODES) {
        int v = rowptr[idx] + bsum[blk];
        rowptr[idx] = v;
        cursor[idx] = v;
    }
}

// fused scatter: dst-CSR key (src,rel), src-CSR key (rel), and zidx map
__global__ __launch_bounds__(256) void scatter_both(
        const int* __restrict__ ei, const int* __restrict__ et,
        int* __restrict__ cur_d, int* __restrict__ cur_s,
        int* __restrict__ skey, int* __restrict__ skey_s,
        int* __restrict__ zidx) {
    int e = blockIdx.x * 256 + threadIdx.x;
    if (e >= E_EDGES) return;
    int s = ei[e], d = ei[E_EDGES + e], rt = et[e];
    int p = atomicAdd(&cur_d[d], 1);
    skey[p] = (s << 6) | rt;                 // dst-order: (src, rel)
    int qp = atomicAdd(&cur_s[s], 1);
    skey_s[qp] = rt;                         // src-order: rel only
    zidx[p] = qp;                            // dst-slot -> Z row (src-slot)
}

// ---- basis [B,K,HID] -> Bt [800, Kp] bf16 RNE, transposed + zero-padded ----
__global__ __launch_bounds__(256) void split_bt_kernel(
        const float* __restrict__ basis, ushort_t* __restrict__ Bt,
        int K, int Kp) {
    int idx = blockIdx.x * 256 + threadIdx.x;   // n*Kp + k
    if (idx >= OUTW * Kp) return;
    int n = idx / Kp, k = idx - n * Kp;
    int b = n / HID, o = n - b * HID;
    float v = 0.f;
    if (k < K) v = basis[((size_t)b * K + k) * HID + o];
    Bt[idx] = f2bf_rne(v);
}

// ---- MFMA GEMM: xbh[M,800](bf16) = A[M,K] * B[K,800] ----
// BM=32, grid 625, full-K A tile staged once; B staged in WIDE stages
// (160 K-cols at a time, 51.2 KB) via block-wide async DMA -> barriers
// drop from 2/K-step to 2/stage (20 total for Kp=320, 10 for Kp=128).
#define BM 32
#define BN 160
#define NCB (OUTW / BN)   // 5
__global__ __launch_bounds__(256) void gemm_mfma(
        const float* __restrict__ A, const ushort_t* __restrict__ Bt,
        ushort_t* __restrict__ xbh, int M, int K, int Kp, int do_relu) {
    __shared__ ushort_t As[BM * 328];   // full-K A, stride SW=Kp+8 (21 KB max)
    __shared__ ushort_t Bs[160 * 160]; // one wide B stage, stride 160 (51.2 KB)
    int tid  = threadIdx.x;
    int lane = tid & 63, wave = tid >> 6;
    int ml = lane & 15, quad = lane >> 4;
    int wr = (wave >> 1) * 16, wc = (wave & 1) * 80;
    int row0 = blockIdx.x * BM;
    int SW = Kp + 8;
    int swb = (Kp >= 160) ? 160 : Kp;   // data K-width per stage
    int nstages = Kp / swb;             // 2 (Kp=320) or 1 (Kp=128)
    int nchunk = swb >> 3;              // real 16B chunks per row (20 or 16)
    int nksl = swb >> 5;                // K-steps per stage (5 or 4)

    // ---- stage FULL-K A tile once: row ra=tid>>3, chunks c=(tid&7)+8i ----
    {
        int ra = tid >> 3;
        int gr = row0 + ra;
        const float* ar = A + (size_t)gr * K;
        for (int c = (tid & 7); c * 8 < Kp; c += 8) {
            int kb = c * 8;
            float vals[8];
            if (gr < M) {
                if (kb + 8 <= K) {
                    float4 f0 = *(const float4*)&ar[kb];
                    float4 f1 = *(const float4*)&ar[kb + 4];
                    vals[0]=f0.x; vals[1]=f0.y; vals[2]=f0.z; vals[3]=f0.w;
                    vals[4]=f1.x; vals[5]=f1.y; vals[6]=f1.z; vals[7]=f1.w;
                } else {
                    #pragma unroll
                    for (int i = 0; i < 8; i++)
                        vals[i] = (kb + i < K) ? ar[kb + i] : 0.f;
                }
                if (do_relu)
                    #pragma unroll
                    for (int i = 0; i < 8; i++) vals[i] = fmaxf(vals[i], 0.f);
            } else {
                #pragma unroll
                for (int i = 0; i < 8; i++) vals[i] = 0.f;
            }
            ushort8 hv;
            #pragma unroll
            for (int i = 0; i < 8; i++) hv[i] = f2bf_rne(vals[i]);
            *(ushort8*)&As[ra * SW + kb] = hv;
        }
    }

    for (int cb = 0; cb < NCB; cb++) {
        int col0 = cb * BN;
        f32x4 acc[5] = {};
        for (int st = 0; st < nstages; st++) {
            __syncthreads();            // protect Bs (and As on first pass)
            // ---- DMA wide B stage: 160 rows x 20 slots x 16B (pad->dummy) ----
            for (int t = tid; t < 3200; t += 256) {
                int rb = t / 20, ch = t - rb * 20;
                const ushort_t* src = (ch < nchunk)
                    ? &Bt[(size_t)(col0 + rb) * Kp + st * swb + ch * 8]
                    : &Bt[0];           // pad slot: harmless dummy
                __builtin_amdgcn_global_load_lds(
                    (const __attribute__((address_space(1))) unsigned int*)src,
                    (__attribute__((address_space(3))) unsigned int*)&Bs[t * 8],
                    16, 0, 0);
            }
            __syncthreads();            // drain DMA
            for (int ksl = 0; ksl < nksl; ksl++) {
                int ka = st * swb + (ksl << 5);
                short8 af = *(const short8*)&As[(wr + ml) * SW + ka + quad * 8];
                #pragma unroll
                for (int nt = 0; nt < 5; nt++) {
                    short8 bfv = *(const short8*)
                        &Bs[(wc + nt * 16 + ml) * 160 + (ksl << 5) + quad * 8];
                    acc[nt] = __builtin_amdgcn_mfma_f32_16x16x32_bf16(af, bfv, acc[nt], 0, 0, 0);
                }
            }
        }
        // epilogue for this column block: bf16 store
        #pragma unroll
        for (int nt = 0; nt < 5; nt++) {
            #pragma unroll
            for (int r = 0; r < 4; r++) {
                int grow = row0 + wr + quad * 4 + r;
                if (grow < M)
                    xbh[(size_t)grow * OUTW + col0 + wc + nt * 16 + ml] =
                        f2bf_rne(acc[nt][r]);
            }
        }
    }
}

// ==== fused per-src-node: xbq/xbk dots + batched-4 Z rows ====
// wave = one src node; lane = eg*16 + c16 covers channels [8*c16, 8*c16+8).
__global__ __launch_bounds__(256) void compute_z(
        const int* __restrict__ rowptr_s, const int* __restrict__ skey_s,
        const float* __restrict__ comp, const ushort_t* __restrict__ xbh,
        const float* __restrict__ q, const float* __restrict__ k,
        ushort_t* __restrict__ Z, float* __restrict__ xbq,
        float* __restrict__ xbk) {
    __shared__ float sq[128], sk[128];
    int tid = threadIdx.x;
    if (tid < 128) {
        sq[tid] = (tid < HID) ? q[tid] : 0.f;
        sk[tid] = (tid < HID) ? k[tid] : 0.f;
    }
    __syncthreads();
    int wave = tid >> 6, lane = tid & 63;
    int s = blockIdx.x * 4 + wave;
    if (s >= N_NODES) return;
    int eg = lane >> 4, c16 = lane & 15;
    int cbase = c16 * 8;
    float xr[NB][8];
    #pragma unroll
    for (int b = 0; b < NB; b++)
        #pragma unroll
        for (int i = 0; i < 8; i++) xr[b][i] = 0.f;
    if (cbase < HID) {
        #pragma unroll
        for (int b = 0; b < NB; b++) {
            const ushort_t* base = xbh + (size_t)s * OUTW + b * HID + cbase;
            ushort4 v0 = *(const ushort4*)base;       // 8B aligned
            xr[b][0] = bf2f(v0.x); xr[b][1] = bf2f(v0.y);
            xr[b][2] = bf2f(v0.z); xr[b][3] = bf2f(v0.w);
            if (cbase + 8 <= HID) {
                ushort4 v1 = *(const ushort4*)(base + 4);
                xr[b][4] = bf2f(v1.x); xr[b][5] = bf2f(v1.y);
                xr[b][6] = bf2f(v1.z); xr[b][7] = bf2f(v1.w);
            }
        }
    }
    // ---- q/k dots: per-base partials over this lane's 8 channels ----
    {
        float pq[NB], pk[NB];
        #pragma unroll
        for (int b = 0; b < NB; b++) {
            float aq = 0.f, ak = 0.f;
            #pragma unroll
            for (int i = 0; i < 8; i++) {
                aq = fmaf(xr[b][i], sq[cbase + i], aq);
                ak = fmaf(xr[b][i], sk[cbase + i], ak);
            }
            pq[b] = aq; pk[b] = ak;
        }
        #pragma unroll
        for (int off = 8; off; off >>= 1)
            #pragma unroll
            for (int b = 0; b < NB; b++) {
                pq[b] += __shfl_xor(pq[b], off);
                pk[b] += __shfl_xor(pk[b], off);
            }
        if (eg == 0) {
            #pragma unroll
            for (int b = 0; b < NB; b++)
                if (c16 == b) {
                    xbq[s * NB + b] = pq[b];
                    xbk[s * NB + b] = pk[b];
                }
        }
    }
    // ---- Z rows, batched 4 edges per iteration ----
    int beg = rowptr_s[s], end = rowptr_s[s + 1];
    for (int p0 = beg; p0 < end; p0 += 4) {
        int p = p0 + eg;
        bool v = p < end;
        int rt = v ? (skey_s[p] & 63) : 0;
        const float* cr = comp + rt * NB;
        float z[8] = {};
        #pragma unroll
        for (int b = 0; b < NB; b++) {
            float cb = cr[b];
            #pragma unroll
            for (int i = 0; i < 8; i++) z[i] = fmaf(cb, xr[b][i], z[i]);
        }
        ushort8 zz;
        #pragma unroll
        for (int i = 0; i < 8; i++) zz[i] = f2bf_rne(z[i]);
        if (v) *(ushort8*)&Z[(size_t)p * ZW + cbase] = zz;   // 16B, coalesced
    }
}

// ==== dst-major: online softmax + paired-edge Z gather + bias ====
__global__ __launch_bounds__(256) void msg_soft(
        const int* __restrict__ rowptr, const int* __restrict__ skey,
        const int* __restrict__ zidx,
        const float* __restrict__ comp, const ushort_t* __restrict__ Z,
        const float* __restrict__ xbq, const float* __restrict__ xbk,
        const float* __restrict__ bias, float* __restrict__ h) {
    int wave = threadIdx.x >> 6, lane = threadIdx.x & 63;
    int d = blockIdx.x * 4 + wave;
    if (d >= N_NODES) return;
    int beg = rowptr[d], end = rowptr[d + 1];

    float4 qd0 = *(const float4*)&xbq[d * NB];
    float4 qd1 = *(const float4*)&xbq[d * NB + 4];

    int l5 = lane & 31;
    bool act = l5 < 25;
    int oc = l5 * 4;                  // channel base (4 channels per lane)
    f32x4 acc = {0.f, 0.f, 0.f, 0.f};
    float m = -1e30f, l = 0.f;

    for (int c0 = beg; c0 < end; c0 += 64) {
        int p = c0 + lane;
        bool valid = p < end;
        float a = -1e30f;
        int zi = 0;
        if (valid) {
            int key = skey[p];
            zi = zidx[p];
            int s = key >> 6, rt = key & 63;
            const float4 c0v = *(const float4*)&comp[rt * NB];
            const float4 c1v = *(const float4*)&comp[rt * NB + 4];
            const float4 k0v = *(const float4*)&xbk[s * NB];
            const float4 k1v = *(const float4*)&xbk[s * NB + 4];
            float qi = c0v.x*qd0.x + c0v.y*qd0.y + c0v.z*qd0.z + c0v.w*qd0.w
                     + c1v.x*qd1.x + c1v.y*qd1.y + c1v.z*qd1.z + c1v.w*qd1.w;
            float kj = c0v.x*k0v.x + c0v.y*k0v.y + c0v.z*k0v.z + c0v.w*k0v.w
                     + c1v.x*k1v.x + c1v.y*k1v.y + c1v.z*k1v.z + c1v.w*k1v.w;
            a = qi + kj;
            a = a > 0.f ? a : 0.2f * a;     // leaky_relu 0.2
        }
        float cm = a;
        #pragma unroll
        for (int off = 32; off; off >>= 1) cm = fmaxf(cm, __shfl_xor(cm, off));
        float M = fmaxf(m, cm);
        float scale = __expf(m - M);
        acc *= scale; l *= scale; m = M;
        float wgt = valid ? __expf(a - M) : 0.f;
        float cs = wgt;
        #pragma unroll
        for (int off = 32; off; off >>= 1) cs += __shfl_xor(cs, off);
        l += cs;
        int cnt = end - c0; if (cnt > 64) cnt = 64;
        for (int j = 0; j < cnt; j += 2) {
            int jj = j + (lane >> 5);         // even half: j, odd half: j+1
            float wj = __shfl(wgt, jj);       // invalid -> 0
            int   zj = __shfl(zi, jj);
            if (act) {
                ushort4 zz = *(const ushort4*)&Z[(size_t)zj * ZW + oc];
                acc.x = fmaf(wj, bf2f(zz.x), acc.x);
                acc.y = fmaf(wj, bf2f(zz.y), acc.y);
                acc.z = fmaf(wj, bf2f(zz.z), acc.z);
                acc.w = fmaf(wj, bf2f(zz.w), acc.w);
            }
        }
    }
    // combine even/odd-edge halves: lane ℓ (<25) += lane ℓ+32
    #pragma unroll
    for (int i = 0; i < 4; i++) acc[i] += __shfl_xor(acc[i], 32);
    if (lane < 25) {
        float inv = 1.f / (l + 1e-16f);
        float4 r;
        r.x = bias[oc]     + acc.x * inv;
        r.y = bias[oc + 1] + acc.y * inv;
        r.z = bias[oc + 2] + acc.z * inv;
        r.w = bias[oc + 3] + acc.w * inv;
        *(float4*)&h[(size_t)d * HID + oc] = r;   // 16B aligned (400|16)
    }
}

// ---- pooled = mean(relu(h2[qidx])); out = pooled @ Wl^T + bl ----
__global__ __launch_bounds__(128) void head_kernel(
        const float* __restrict__ h2, const int* __restrict__ qidx,
        const float* __restrict__ Wl, const float* __restrict__ bl,
        float* __restrict__ out) {
    __shared__ float pooled[HID];
    int tid = threadIdx.x;
    if (tid < HID) {
        float s = 0.f;
        for (int i = 0; i < NQ; i++)
            s += fmaxf(h2[(size_t)qidx[i] * HID + tid], 0.f);
        pooled[tid] = s * (1.0f / NQ);
    }
    __syncthreads();
    if (tid < CLS) {
        float s = bl[tid];
        for (int o = 0; o < HID; o++) s = fmaf(pooled[o], Wl[tid * HID + o], s);
        out[tid] = s;
    }
}

extern "C" void kernel_launch(void* const* d_in, const int* in_sizes, int n_in,
                              void* d_out, int out_size, void* d_ws, size_t ws_size,
                              hipStream_t stream) {
    const float* x      = (const float*)d_in[0];
    const int*   ei     = (const int*)  d_in[1];
    const int*   et     = (const int*)  d_in[2];
    const int*   qidx   = (const int*)  d_in[3];
    const float* comp1  = (const float*)d_in[4];
    const float* basis1 = (const float*)d_in[5];
    const float* q1     = (const float*)d_in[6];
    const float* k1     = (const float*)d_in[7];
    const float* b1     = (const float*)d_in[8];
    const float* comp2  = (const float*)d_in[9];
    const float* basis2 = (const float*)d_in[10];
    const float* q2     = (const float*)d_in[11];
    const float* k2     = (const float*)d_in[12];
    const float* b2     = (const float*)d_in[13];
    const float* Wl     = (const float*)d_in[14];
    const float* bl     = (const float*)d_in[15];
    float* out = (float*)d_out;

    const int KP1 = 320, KP2 = 128;

    char* w = (char*)d_ws;
    size_t off = 0;
    auto alloc = [&](size_t nbytes) {
        void* p = (void*)(w + off);
        off += ((nbytes + 255) / 256) * 256;
        return p;
    };
    ushort_t* xbh    = (ushort_t*)alloc((size_t)N_NODES * OUTW * 2); // 32 MB
    ushort_t* Z      = (ushort_t*)alloc((size_t)E_EDGES * ZW * 2);   // 82 MB
    float*    h1     = (float*)alloc((size_t)N_NODES * HID * 4);     // 8 MB
    float*    h2     = (float*)alloc((size_t)N_NODES * HID * 4);     // 8 MB
    ushort_t* Bt     = (ushort_t*)alloc((size_t)OUTW * KP1 * 2);     // 0.5 MB
    float*    xbq    = (float*)alloc((size_t)N_NODES * NB * 4);
    float*    xbk    = (float*)alloc((size_t)N_NODES * NB * 4);
    int*      deg_d  = (int*)alloc(N_NODES * 4);
    int*      deg_s  = (int*)alloc(N_NODES * 4);
    int*      rp_d   = (int*)alloc((N_NODES + 1) * 4);
    int*      rp_s   = (int*)alloc((N_NODES + 1) * 4);
    int*      cur_d  = (int*)alloc(N_NODES * 4);
    int*      cur_s  = (int*)alloc(N_NODES * 4);
    int*      bsum_d = (int*)alloc(SCAN_BLKS * 4);
    int*      bsum_s = (int*)alloc(SCAN_BLKS * 4);
    int*      skey   = (int*)alloc(E_EDGES * 4);
    int*      skey_s = (int*)alloc(E_EDGES * 4);
    int*      zidx   = (int*)alloc(E_EDGES * 4);

    // ---- CSR build (once; same graph both layers) ----
    zero_deg2<<<SCAN_BLKS, 256, 0, stream>>>(deg_d, deg_s);
    hist2_kernel<<<(E_EDGES + 255) / 256, 256, 0, stream>>>(ei, deg_d, deg_s);
    scan1_both<<<2 * SCAN_BLKS, 256, 0, stream>>>(deg_d, rp_d, bsum_d, deg_s, rp_s, bsum_s);
    scan2_both<<<2, 128, 0, stream>>>(bsum_d, rp_d, bsum_s, rp_s);
    scan3_both<<<2 * SCAN_BLKS, 256, 0, stream>>>(rp_d, bsum_d, cur_d, rp_s, bsum_s, cur_s);
    scatter_both<<<(E_EDGES + 255) / 256, 256, 0, stream>>>(ei, et, cur_d, cur_s, skey, skey_s, zidx);

    auto layer = [&](const float* input, int K, int Kp, int relu_in,
                     const float* comp, const float* basis, const float* q,
                     const float* k, const float* bias, float* hout) {
        int nb = OUTW * Kp;
        split_bt_kernel<<<(nb + 255) / 256, 256, 0, stream>>>(basis, Bt, K, Kp);
        gemm_mfma<<<(N_NODES + BM - 1) / BM, 256, 0, stream>>>(input, Bt, xbh, N_NODES, K, Kp, relu_in);
        compute_z<<<(N_NODES + 3) / 4, 256, 0, stream>>>(rp_s, skey_s, comp, xbh, q, k, Z, xbq, xbk);
        msg_soft<<<(N_NODES + 3) / 4, 256, 0, stream>>>(rp_d, skey, zidx, comp, Z, xbq, xbk, bias, hout);
    };

    layer(x,  IN_CH, KP1, 0, comp1, basis1, q1, k1, b1, h1);
    layer(h1, HID,   KP2, 1, comp2, basis2, q2, k2, b2, h2);
    head_kernel<<<1, 128, 0, stream>>>(h2, qidx, Wl, bl, out);
}

// Round 15
// 380.754 us; speedup vs baseline: 1.0737x; 1.0737x over previous
//
#include <hip/hip_runtime.h>
#include <math.h>

#define N_NODES 20000
#define E_EDGES 320000
#define IN_CH   300
#define HID     100
#define R_REL   50
#define NB      8
#define CLS     3
#define NQ      64
#define OUTW    800   // NB * HID
#define ZW      128   // Z row stride (ushorts): 256-B rows, batched-4 writes
#define SCAN_BLKS ((N_NODES + 255) / 256)   // 79

typedef unsigned short ushort_t;
typedef __attribute__((ext_vector_type(8))) short     short8;
typedef __attribute__((ext_vector_type(8))) unsigned short ushort8;
typedef __attribute__((ext_vector_type(4))) float     f32x4;
typedef __attribute__((ext_vector_type(2))) float     f32x2;

__device__ __forceinline__ ushort_t f2bf_rne(float f) {   // round-nearest-even
    unsigned u = __float_as_uint(f);
    unsigned r = (u + 0x7fffu + ((u >> 16) & 1u)) >> 16;
    return (ushort_t)r;
}
__device__ __forceinline__ float bf2f(ushort_t u) {
    return __uint_as_float((unsigned)u << 16);
}

// ============================ CSR build =================================
__global__ __launch_bounds__(256) void zero_deg2(int* __restrict__ dd,
                                                 int* __restrict__ ds) {
    int i = blockIdx.x * 256 + threadIdx.x;
    if (i < N_NODES) { dd[i] = 0; ds[i] = 0; }
}

__global__ __launch_bounds__(256) void hist2_kernel(
        const int* __restrict__ ei, int* __restrict__ dd,
        int* __restrict__ ds) {
    int e = blockIdx.x * 256 + threadIdx.x;
    if (e < E_EDGES) {
        atomicAdd(&dd[ei[E_EDGES + e]], 1);
        atomicAdd(&ds[ei[e]], 1);
    }
}

// dual-set scans: blockIdx selects (deg_d...) or (deg_s...) set
__global__ __launch_bounds__(256) void scan1_both(
        const int* __restrict__ deg_d, int* __restrict__ rp_d, int* __restrict__ bsum_d,
        const int* __restrict__ deg_s, int* __restrict__ rp_s, int* __restrict__ bsum_s) {
    int set = blockIdx.x / SCAN_BLKS, blk = blockIdx.x % SCAN_BLKS;
    const int* deg = set ? deg_s : deg_d;
    int* rowptr    = set ? rp_s  : rp_d;
    int* bsum      = set ? bsum_s : bsum_d;
    __shared__ int s[256];
    int tid = threadIdx.x;
    int idx = blk * 256 + tid;
    int v = (idx < N_NODES) ? deg[idx] : 0;
    s[tid] = v; __syncthreads();
    #pragma unroll
    for (int off = 1; off < 256; off <<= 1) {
        int t = (tid >= off) ? s[tid - off] : 0;
        __syncthreads();
        s[tid] += t;
        __syncthreads();
    }
    if (idx < N_NODES) rowptr[idx] = s[tid] - v;   // exclusive
    if (tid == 255) bsum[blk] = s[255];
}

__global__ __launch_bounds__(128) void scan2_both(
        int* __restrict__ bsum_d, int* __restrict__ rp_d,
        int* __restrict__ bsum_s, int* __restrict__ rp_s) {
    int* bsum   = blockIdx.x ? bsum_s : bsum_d;
    int* rowptr = blockIdx.x ? rp_s   : rp_d;
    __shared__ int s[128];
    int tid = threadIdx.x;
    int v = (tid < SCAN_BLKS) ? bsum[tid] : 0;
    s[tid] = v; __syncthreads();
    #pragma unroll
    for (int off = 1; off < 128; off <<= 1) {
        int t = (tid >= off) ? s[tid - off] : 0;
        __syncthreads();
        s[tid] += t;
        __syncthreads();
    }
    if (tid < SCAN_BLKS) bsum[tid] = s[tid] - v;   // exclusive
    if (tid == 0) rowptr[N_NODES] = E_EDGES;
}

__global__ __launch_bounds__(256) void scan3_both(
        int* __restrict__ rp_d, const int* __restrict__ bsum_d, int* __restrict__ cur_d,
        int* __restrict__ rp_s, const int* __restrict__ bsum_s, int* __restrict__ cur_s) {
    int set = blockIdx.x / SCAN_BLKS, blk = blockIdx.x % SCAN_BLKS;
    int* rowptr      = set ? rp_s   : rp_d;
    const int* bsum  = set ? bsum_s : bsum_d;
    int* cursor      = set ? cur_s  : cur_d;
    int idx = blk * 256 + threadIdx.x;
    if (idx < N_NODES) {
        int v = rowptr[idx] + bsum[blk];
        rowptr[idx] = v;
        cursor[idx] = v;
    }
}

// fused scatter: dst-CSR key (src,rel), src-CSR key (rel), and zidx map
__global__ __launch_bounds__(256) void scatter_both(
        const int* __restrict__ ei, const int* __restrict__ et,
        int* __restrict__ cur_d, int* __restrict__ cur_s,
        int* __restrict__ skey, int* __restrict__ skey_s,
        int* __restrict__ zidx) {
    int e = blockIdx.x * 256 + threadIdx.x;
    if (e >= E_EDGES) return;
    int s = ei[e], d = ei[E_EDGES + e], rt = et[e];
    int p = atomicAdd(&cur_d[d], 1);
    skey[p] = (s << 6) | rt;                 // dst-order: (src, rel)
    int qp = atomicAdd(&cur_s[s], 1);
    skey_s[qp] = rt;                         // src-order: rel only
    zidx[p] = qp;                            // dst-slot -> Z row (src-slot)
}

// ---- basis [B,K,HID] -> Bt [800, Kp] bf16 RNE, transposed + zero-padded ----
__global__ __launch_bounds__(256) void split_bt_kernel(
        const float* __restrict__ basis, ushort_t* __restrict__ Bt,
        int K, int Kp) {
    int idx = blockIdx.x * 256 + threadIdx.x;   // n*Kp + k
    if (idx >= OUTW * Kp) return;
    int n = idx / Kp, k = idx - n * Kp;
    int b = n / HID, o = n - b * HID;
    float v = 0.f;
    if (k < K) v = basis[((size_t)b * K + k) * HID + o];
    Bt[idx] = f2bf_rne(v);
}

// ---- MFMA GEMM: xbh[M,800](bf16) = A[M,K] * B[K,800] ----
// Best measured structure (round-13): BM=32, grid 625, full-K A tile staged
// once; B tiles per K-step via block-wide async global_load_lds DMA;
// column blocks looped inside (A FETCH stays ~14 MB).
#define BM 32
#define BN 160
#define NCB (OUTW / BN)   // 5
__global__ __launch_bounds__(256) void gemm_mfma(
        const float* __restrict__ A, const ushort_t* __restrict__ Bt,
        ushort_t* __restrict__ xbh, int M, int K, int Kp, int do_relu) {
    __shared__ ushort_t As[BM * 328];   // max Kp=320 -> stride 328
    __shared__ ushort_t Bs[BN * 32];    // 10 KB
    int tid  = threadIdx.x;
    int lane = tid & 63, wave = tid >> 6;
    int ml = lane & 15, quad = lane >> 4;
    int wr = (wave >> 1) * 16, wc = (wave & 1) * 80;
    int row0 = blockIdx.x * BM;
    int SW = Kp + 8;                    // A LDS row stride (ushorts)
    int ksteps = Kp >> 5;

    // ---- stage FULL-K A tile once: row ra=tid>>3, chunks c=(tid&7)+8i ----
    {
        int ra = tid >> 3;
        int gr = row0 + ra;
        const float* ar = A + (size_t)gr * K;
        for (int c = (tid & 7); c * 8 < Kp; c += 8) {
            int kb = c * 8;
            float vals[8];
            if (gr < M) {
                if (kb + 8 <= K) {
                    float4 f0 = *(const float4*)&ar[kb];
                    float4 f1 = *(const float4*)&ar[kb + 4];
                    vals[0]=f0.x; vals[1]=f0.y; vals[2]=f0.z; vals[3]=f0.w;
                    vals[4]=f1.x; vals[5]=f1.y; vals[6]=f1.z; vals[7]=f1.w;
                } else {
                    #pragma unroll
                    for (int i = 0; i < 8; i++)
                        vals[i] = (kb + i < K) ? ar[kb + i] : 0.f;
                }
                if (do_relu)
                    #pragma unroll
                    for (int i = 0; i < 8; i++) vals[i] = fmaxf(vals[i], 0.f);
            } else {
                #pragma unroll
                for (int i = 0; i < 8; i++) vals[i] = 0.f;
            }
            ushort8 hv;
            #pragma unroll
            for (int i = 0; i < 8; i++) hv[i] = f2bf_rne(vals[i]);
            *(ushort8*)&As[ra * SW + kb] = hv;
        }
    }

    for (int cb = 0; cb < NCB; cb++) {
        int col0 = cb * BN;
        f32x4 acc[5] = {};
        for (int ks = 0; ks < ksteps; ks++) {
            int k0 = ks << 5;
            __syncthreads();            // protect Bs (and As on first pass)
            // ---- stage B tile via async DMA: 640 tasks x 16B ----
            for (int t = tid; t < 640; t += 256) {
                int rb = t >> 2, ch = t & 3;
                __builtin_amdgcn_global_load_lds(
                    (const __attribute__((address_space(1))) unsigned int*)
                        &Bt[(size_t)(col0 + rb) * Kp + k0 + ch * 8],
                    (__attribute__((address_space(3))) unsigned int*)&Bs[t * 8],
                    16, 0, 0);
            }
            __syncthreads();            // compiler drains vmcnt before barrier
            short8 af, bf[5];
            af = *(const short8*)&As[(wr + ml) * SW + k0 + quad * 8];
            #pragma unroll
            for (int nt = 0; nt < 5; nt++)
                bf[nt] = *(const short8*)&Bs[(wc + nt * 16 + ml) * 32 + quad * 8];
            #pragma unroll
            for (int nt = 0; nt < 5; nt++)
                acc[nt] = __builtin_amdgcn_mfma_f32_16x16x32_bf16(af, bf[nt], acc[nt], 0, 0, 0);
        }
        // epilogue for this column block: bf16 store
        #pragma unroll
        for (int nt = 0; nt < 5; nt++) {
            #pragma unroll
            for (int r = 0; r < 4; r++) {
                int grow = row0 + wr + quad * 4 + r;
                if (grow < M)
                    xbh[(size_t)grow * OUTW + col0 + wc + nt * 16 + ml] =
                        f2bf_rne(acc[nt][r]);
            }
        }
    }
}

// ==== fused per-src-node: xbq/xbk dots + batched-4 Z rows ====
// wave = one src node; lane = eg*16 + c16 covers channels [8*c16, 8*c16+8).
__global__ __launch_bounds__(256) void compute_z(
        const int* __restrict__ rowptr_s, const int* __restrict__ skey_s,
        const float* __restrict__ comp, const ushort_t* __restrict__ xbh,
        const float* __restrict__ q, const float* __restrict__ k,
        ushort_t* __restrict__ Z, float* __restrict__ xbq,
        float* __restrict__ xbk) {
    __shared__ float sq[128], sk[128];
    int tid = threadIdx.x;
    if (tid < 128) {
        sq[tid] = (tid < HID) ? q[tid] : 0.f;
        sk[tid] = (tid < HID) ? k[tid] : 0.f;
    }
    __syncthreads();
    int wave = tid >> 6, lane = tid & 63;
    int s = blockIdx.x * 4 + wave;
    if (s >= N_NODES) return;
    int eg = lane >> 4, c16 = lane & 15;
    int cbase = c16 * 8;
    float xr[NB][8];
    #pragma unroll
    for (int b = 0; b < NB; b++)
        #pragma unroll
        for (int i = 0; i < 8; i++) xr[b][i] = 0.f;
    if (cbase < HID) {
        #pragma unroll
        for (int b = 0; b < NB; b++) {
            const ushort_t* base = xbh + (size_t)s * OUTW + b * HID + cbase;
            ushort4 v0 = *(const ushort4*)base;       // 8B aligned
            xr[b][0] = bf2f(v0.x); xr[b][1] = bf2f(v0.y);
            xr[b][2] = bf2f(v0.z); xr[b][3] = bf2f(v0.w);
            if (cbase + 8 <= HID) {
                ushort4 v1 = *(const ushort4*)(base + 4);
                xr[b][4] = bf2f(v1.x); xr[b][5] = bf2f(v1.y);
                xr[b][6] = bf2f(v1.z); xr[b][7] = bf2f(v1.w);
            }
        }
    }
    // ---- q/k dots: per-base partials over this lane's 8 channels ----
    {
        float pq[NB], pk[NB];
        #pragma unroll
        for (int b = 0; b < NB; b++) {
            float aq = 0.f, ak = 0.f;
            #pragma unroll
            for (int i = 0; i < 8; i++) {
                aq = fmaf(xr[b][i], sq[cbase + i], aq);
                ak = fmaf(xr[b][i], sk[cbase + i], ak);
            }
            pq[b] = aq; pk[b] = ak;
        }
        #pragma unroll
        for (int off = 8; off; off >>= 1)
            #pragma unroll
            for (int b = 0; b < NB; b++) {
                pq[b] += __shfl_xor(pq[b], off);
                pk[b] += __shfl_xor(pk[b], off);
            }
        if (eg == 0) {
            #pragma unroll
            for (int b = 0; b < NB; b++)
                if (c16 == b) {
                    xbq[s * NB + b] = pq[b];
                    xbk[s * NB + b] = pk[b];
                }
        }
    }
    // ---- Z rows, batched 4 edges per iteration ----
    int beg = rowptr_s[s], end = rowptr_s[s + 1];
    for (int p0 = beg; p0 < end; p0 += 4) {
        int p = p0 + eg;
        bool v = p < end;
        int rt = v ? (skey_s[p] & 63) : 0;
        const float* cr = comp + rt * NB;
        float z[8] = {};
        #pragma unroll
        for (int b = 0; b < NB; b++) {
            float cb = cr[b];
            #pragma unroll
            for (int i = 0; i < 8; i++) z[i] = fmaf(cb, xr[b][i], z[i]);
        }
        ushort8 zz;
        #pragma unroll
        for (int i = 0; i < 8; i++) zz[i] = f2bf_rne(z[i]);
        if (v) *(ushort8*)&Z[(size_t)p * ZW + cbase] = zz;   // 16B, coalesced
    }
}

// ==== dst-major: online softmax + paired-edge Z gather + bias ====
__global__ __launch_bounds__(256) void msg_soft(
        const int* __restrict__ rowptr, const int* __restrict__ skey,
        const int* __restrict__ zidx,
        const float* __restrict__ comp, const ushort_t* __restrict__ Z,
        const float* __restrict__ xbq, const float* __restrict__ xbk,
        const float* __restrict__ bias, float* __restrict__ h) {
    int wave = threadIdx.x >> 6, lane = threadIdx.x & 63;
    int d = blockIdx.x * 4 + wave;
    if (d >= N_NODES) return;
    int beg = rowptr[d], end = rowptr[d + 1];

    float4 qd0 = *(const float4*)&xbq[d * NB];
    float4 qd1 = *(const float4*)&xbq[d * NB + 4];

    int l5 = lane & 31;
    bool act = l5 < 25;
    int oc = l5 * 4;                  // channel base (4 channels per lane)
    f32x4 acc = {0.f, 0.f, 0.f, 0.f};
    float m = -1e30f, l = 0.f;

    for (int c0 = beg; c0 < end; c0 += 64) {
        int p = c0 + lane;
        bool valid = p < end;
        float a = -1e30f;
        int zi = 0;
        if (valid) {
            int key = skey[p];
            zi = zidx[p];
            int s = key >> 6, rt = key & 63;
            const float4 c0v = *(const float4*)&comp[rt * NB];
            const float4 c1v = *(const float4*)&comp[rt * NB + 4];
            const float4 k0v = *(const float4*)&xbk[s * NB];
            const float4 k1v = *(const float4*)&xbk[s * NB + 4];
            float qi = c0v.x*qd0.x + c0v.y*qd0.y + c0v.z*qd0.z + c0v.w*qd0.w
                     + c1v.x*qd1.x + c1v.y*qd1.y + c1v.z*qd1.z + c1v.w*qd1.w;
            float kj = c0v.x*k0v.x + c0v.y*k0v.y + c0v.z*k0v.z + c0v.w*k0v.w
                     + c1v.x*k1v.x + c1v.y*k1v.y + c1v.z*k1v.z + c1v.w*k1v.w;
            a = qi + kj;
            a = a > 0.f ? a : 0.2f * a;     // leaky_relu 0.2
        }
        float cm = a;
        #pragma unroll
        for (int off = 32; off; off >>= 1) cm = fmaxf(cm, __shfl_xor(cm, off));
        float M = fmaxf(m, cm);
        float scale = __expf(m - M);
        acc *= scale; l *= scale; m = M;
        float wgt = valid ? __expf(a - M) : 0.f;
        float cs = wgt;
        #pragma unroll
        for (int off = 32; off; off >>= 1) cs += __shfl_xor(cs, off);
        l += cs;
        int cnt = end - c0; if (cnt > 64) cnt = 64;
        for (int j = 0; j < cnt; j += 2) {
            int jj = j + (lane >> 5);         // even half: j, odd half: j+1
            float wj = __shfl(wgt, jj);       // invalid -> 0
            int   zj = __shfl(zi, jj);
            if (act) {
                ushort4 zz = *(const ushort4*)&Z[(size_t)zj * ZW + oc];
                acc.x = fmaf(wj, bf2f(zz.x), acc.x);
                acc.y = fmaf(wj, bf2f(zz.y), acc.y);
                acc.z = fmaf(wj, bf2f(zz.z), acc.z);
                acc.w = fmaf(wj, bf2f(zz.w), acc.w);
            }
        }
    }
    // combine even/odd-edge halves: lane ℓ (<25) += lane ℓ+32
    #pragma unroll
    for (int i = 0; i < 4; i++) acc[i] += __shfl_xor(acc[i], 32);
    if (lane < 25) {
        float inv = 1.f / (l + 1e-16f);
        float4 r;
        r.x = bias[oc]     + acc.x * inv;
        r.y = bias[oc + 1] + acc.y * inv;
        r.z = bias[oc + 2] + acc.z * inv;
        r.w = bias[oc + 3] + acc.w * inv;
        *(float4*)&h[(size_t)d * HID + oc] = r;   // 16B aligned (400|16)
    }
}

// ---- pooled = mean(relu(h2[qidx])); out = pooled @ Wl^T + bl ----
__global__ __launch_bounds__(128) void head_kernel(
        const float* __restrict__ h2, const int* __restrict__ qidx,
        const float* __restrict__ Wl, const float* __restrict__ bl,
        float* __restrict__ out) {
    __shared__ float pooled[HID];
    int tid = threadIdx.x;
    if (tid < HID) {
        float s = 0.f;
        for (int i = 0; i < NQ; i++)
            s += fmaxf(h2[(size_t)qidx[i] * HID + tid], 0.f);
        pooled[tid] = s * (1.0f / NQ);
    }
    __syncthreads();
    if (tid < CLS) {
        float s = bl[tid];
        for (int o = 0; o < HID; o++) s = fmaf(pooled[o], Wl[tid * HID + o], s);
        out[tid] = s;
    }
}

extern "C" void kernel_launch(void* const* d_in, const int* in_sizes, int n_in,
                              void* d_out, int out_size, void* d_ws, size_t ws_size,
                              hipStream_t stream) {
    const float* x      = (const float*)d_in[0];
    const int*   ei     = (const int*)  d_in[1];
    const int*   et     = (const int*)  d_in[2];
    const int*   qidx   = (const int*)  d_in[3];
    const float* comp1  = (const float*)d_in[4];
    const float* basis1 = (const float*)d_in[5];
    const float* q1     = (const float*)d_in[6];
    const float* k1     = (const float*)d_in[7];
    const float* b1     = (const float*)d_in[8];
    const float* comp2  = (const float*)d_in[9];
    const float* basis2 = (const float*)d_in[10];
    const float* q2     = (const float*)d_in[11];
    const float* k2     = (const float*)d_in[12];
    const float* b2     = (const float*)d_in[13];
    const float* Wl     = (const float*)d_in[14];
    const float* bl     = (const float*)d_in[15];
    float* out = (float*)d_out;

    const int KP1 = 320, KP2 = 128;

    char* w = (char*)d_ws;
    size_t off = 0;
    auto alloc = [&](size_t nbytes) {
        void* p = (void*)(w + off);
        off += ((nbytes + 255) / 256) * 256;
        return p;
    };
    ushort_t* xbh    = (ushort_t*)alloc((size_t)N_NODES * OUTW * 2); // 32 MB
    ushort_t* Z      = (ushort_t*)alloc((size_t)E_EDGES * ZW * 2);   // 82 MB
    float*    h1     = (float*)alloc((size_t)N_NODES * HID * 4);     // 8 MB
    float*    h2     = (float*)alloc((size_t)N_NODES * HID * 4);     // 8 MB
    ushort_t* Bt     = (ushort_t*)alloc((size_t)OUTW * KP1 * 2);     // 0.5 MB
    float*    xbq    = (float*)alloc((size_t)N_NODES * NB * 4);
    float*    xbk    = (float*)alloc((size_t)N_NODES * NB * 4);
    int*      deg_d  = (int*)alloc(N_NODES * 4);
    int*      deg_s  = (int*)alloc(N_NODES * 4);
    int*      rp_d   = (int*)alloc((N_NODES + 1) * 4);
    int*      rp_s   = (int*)alloc((N_NODES + 1) * 4);
    int*      cur_d  = (int*)alloc(N_NODES * 4);
    int*      cur_s  = (int*)alloc(N_NODES * 4);
    int*      bsum_d = (int*)alloc(SCAN_BLKS * 4);
    int*      bsum_s = (int*)alloc(SCAN_BLKS * 4);
    int*      skey   = (int*)alloc(E_EDGES * 4);
    int*      skey_s = (int*)alloc(E_EDGES * 4);
    int*      zidx   = (int*)alloc(E_EDGES * 4);

    // ---- CSR build (once; same graph both layers) ----
    zero_deg2<<<SCAN_BLKS, 256, 0, stream>>>(deg_d, deg_s);
    hist2_kernel<<<(E_EDGES + 255) / 256, 256, 0, stream>>>(ei, deg_d, deg_s);
    scan1_both<<<2 * SCAN_BLKS, 256, 0, stream>>>(deg_d, rp_d, bsum_d, deg_s, rp_s, bsum_s);
    scan2_both<<<2, 128, 0, stream>>>(bsum_d, rp_d, bsum_s, rp_s);
    scan3_both<<<2 * SCAN_BLKS, 256, 0, stream>>>(rp_d, bsum_d, cur_d, rp_s, bsum_s, cur_s);
    scatter_both<<<(E_EDGES + 255) / 256, 256, 0, stream>>>(ei, et, cur_d, cur_s, skey, skey_s, zidx);

    auto layer = [&](const float* input, int K, int Kp, int relu_in,
                     const float* comp, const float* basis, const float* q,
                     const float* k, const float* bias, float* hout) {
        int nb = OUTW * Kp;
        split_bt_kernel<<<(nb + 255) / 256, 256, 0, stream>>>(basis, Bt, K, Kp);
        gemm_mfma<<<(N_NODES + BM - 1) / BM, 256, 0, stream>>>(input, Bt, xbh, N_NODES, K, Kp, relu_in);
        compute_z<<<(N_NODES + 3) / 4, 256, 0, stream>>>(rp_s, skey_s, comp, xbh, q, k, Z, xbq, xbk);
        msg_soft<<<(N_NODES + 3) / 4, 256, 0, stream>>>(rp_d, skey, zidx, comp, Z, xbq, xbk, bias, hout);
    };

    layer(x,  IN_CH, KP1, 0, comp1, basis1, q1, k1, b1, h1);
    layer(h1, HID,   KP2, 1, comp2, basis2, q2, k2, b2, h2);
    head_kernel<<<1, 128, 0, stream>>>(h2, qidx, Wl, bl, out);
}

// Round 16
// 366.517 us; speedup vs baseline: 1.1154x; 1.0388x over previous
//
#include <hip/hip_runtime.h>
#include <math.h>

#define N_NODES 20000
#define E_EDGES 320000
#define IN_CH   300
#define HID     100
#define R_REL   50
#define NB      8
#define CLS     3
#define NQ      64
#define OUTW    800   // NB * HID
#define ZW      128   // Z row stride (ushorts): 256-B rows, batched-4 writes
#define KP1     320
#define KP2     128
#define SCAN_BLKS ((N_NODES + 255) / 256)   // 79

typedef unsigned short ushort_t;
typedef __attribute__((ext_vector_type(8))) short     short8;
typedef __attribute__((ext_vector_type(8))) unsigned short ushort8;
typedef __attribute__((ext_vector_type(4))) float     f32x4;
typedef __attribute__((ext_vector_type(2))) float     f32x2;

__device__ __forceinline__ ushort_t f2bf_rne(float f) {   // round-nearest-even
    unsigned u = __float_as_uint(f);
    unsigned r = (u + 0x7fffu + ((u >> 16) & 1u)) >> 16;
    return (ushort_t)r;
}
__device__ __forceinline__ float bf2f(ushort_t u) {
    return __uint_as_float((unsigned)u << 16);
}

// ============================ CSR build =================================
__global__ __launch_bounds__(256) void zero_deg2(int* __restrict__ dd,
                                                 int* __restrict__ ds) {
    int i = blockIdx.x * 256 + threadIdx.x;
    if (i < N_NODES) { dd[i] = 0; ds[i] = 0; }
}

__global__ __launch_bounds__(256) void hist2_kernel(
        const int* __restrict__ ei, int* __restrict__ dd,
        int* __restrict__ ds) {
    int e = blockIdx.x * 256 + threadIdx.x;
    if (e < E_EDGES) {
        atomicAdd(&dd[ei[E_EDGES + e]], 1);
        atomicAdd(&ds[ei[e]], 1);
    }
}

// dual-set scans: blockIdx selects (deg_d...) or (deg_s...) set
__global__ __launch_bounds__(256) void scan1_both(
        const int* __restrict__ deg_d, int* __restrict__ rp_d, int* __restrict__ bsum_d,
        const int* __restrict__ deg_s, int* __restrict__ rp_s, int* __restrict__ bsum_s) {
    int set = blockIdx.x / SCAN_BLKS, blk = blockIdx.x % SCAN_BLKS;
    const int* deg = set ? deg_s : deg_d;
    int* rowptr    = set ? rp_s  : rp_d;
    int* bsum      = set ? bsum_s : bsum_d;
    __shared__ int s[256];
    int tid = threadIdx.x;
    int idx = blk * 256 + tid;
    int v = (idx < N_NODES) ? deg[idx] : 0;
    s[tid] = v; __syncthreads();
    #pragma unroll
    for (int off = 1; off < 256; off <<= 1) {
        int t = (tid >= off) ? s[tid - off] : 0;
        __syncthreads();
        s[tid] += t;
        __syncthreads();
    }
    if (idx < N_NODES) rowptr[idx] = s[tid] - v;   // exclusive
    if (tid == 255) bsum[blk] = s[255];
}

__global__ __launch_bounds__(128) void scan2_both(
        int* __restrict__ bsum_d, int* __restrict__ rp_d,
        int* __restrict__ bsum_s, int* __restrict__ rp_s) {
    int* bsum   = blockIdx.x ? bsum_s : bsum_d;
    int* rowptr = blockIdx.x ? rp_s   : rp_d;
    __shared__ int s[128];
    int tid = threadIdx.x;
    int v = (tid < SCAN_BLKS) ? bsum[tid] : 0;
    s[tid] = v; __syncthreads();
    #pragma unroll
    for (int off = 1; off < 128; off <<= 1) {
        int t = (tid >= off) ? s[tid - off] : 0;
        __syncthreads();
        s[tid] += t;
        __syncthreads();
    }
    if (tid < SCAN_BLKS) bsum[tid] = s[tid] - v;   // exclusive
    if (tid == 0) rowptr[N_NODES] = E_EDGES;
}

__global__ __launch_bounds__(256) void scan3_both(
        int* __restrict__ rp_d, const int* __restrict__ bsum_d, int* __restrict__ cur_d,
        int* __restrict__ rp_s, const int* __restrict__ bsum_s, int* __restrict__ cur_s) {
    int set = blockIdx.x / SCAN_BLKS, blk = blockIdx.x % SCAN_BLKS;
    int* rowptr      = set ? rp_s   : rp_d;
    const int* bsum  = set ? bsum_s : bsum_d;
    int* cursor      = set ? cur_s  : cur_d;
    int idx = blk * 256 + threadIdx.x;
    if (idx < N_NODES) {
        int v = rowptr[idx] + bsum[blk];
        rowptr[idx] = v;
        cursor[idx] = v;
    }
}

// fused scatter: dst-CSR key (src,rel), src-CSR key (rel), and zidx map
__global__ __launch_bounds__(256) void scatter_both(
        const int* __restrict__ ei, const int* __restrict__ et,
        int* __restrict__ cur_d, int* __restrict__ cur_s,
        int* __restrict__ skey, int* __restrict__ skey_s,
        int* __restrict__ zidx) {
    int e = blockIdx.x * 256 + threadIdx.x;
    if (e >= E_EDGES) return;
    int s = ei[e], d = ei[E_EDGES + e], rt = et[e];
    int p = atomicAdd(&cur_d[d], 1);
    skey[p] = (s << 6) | rt;                 // dst-order: (src, rel)
    int qp = atomicAdd(&cur_s[s], 1);
    skey_s[qp] = rt;                         // src-order: rel only
    zidx[p] = qp;                            // dst-slot -> Z row (src-slot)
}

// ---- both layers' basis -> Bt (transposed bf16, zero-padded), one dispatch ----
__global__ __launch_bounds__(256) void split_bt_both(
        const float* __restrict__ basis1, ushort_t* __restrict__ Bt1,
        const float* __restrict__ basis2, ushort_t* __restrict__ Bt2) {
    int idx = blockIdx.x * 256 + threadIdx.x;
    const int n1 = OUTW * KP1;
    if (idx < n1) {
        int n = idx / KP1, k = idx - n * KP1;
        int b = n / HID, o = n - b * HID;
        float v = (k < IN_CH) ? basis1[((size_t)b * IN_CH + k) * HID + o] : 0.f;
        Bt1[idx] = f2bf_rne(v);
    } else {
        int i2 = idx - n1;
        if (i2 >= OUTW * KP2) return;
        int n = i2 / KP2, k = i2 - n * KP2;
        int b = n / HID, o = n - b * HID;
        float v = (k < HID) ? basis2[((size_t)b * HID + k) * HID + o] : 0.f;
        Bt2[i2] = f2bf_rne(v);
    }
}

// ---- MFMA GEMM: xbh[M,800](bf16) = A[M,K] * B[K,800] ----
// Best measured structure (round-13): BM=32, grid 625, full-K A tile staged
// once; B tiles per K-step via block-wide async global_load_lds DMA;
// column blocks looped inside (A FETCH stays ~14 MB).
#define BM 32
#define BN 160
#define NCB (OUTW / BN)   // 5
__global__ __launch_bounds__(256) void gemm_mfma(
        const float* __restrict__ A, const ushort_t* __restrict__ Bt,
        ushort_t* __restrict__ xbh, int M, int K, int Kp, int do_relu) {
    __shared__ ushort_t As[BM * 328];   // max Kp=320 -> stride 328
    __shared__ ushort_t Bs[BN * 32];    // 10 KB
    int tid  = threadIdx.x;
    int lane = tid & 63, wave = tid >> 6;
    int ml = lane & 15, quad = lane >> 4;
    int wr = (wave >> 1) * 16, wc = (wave & 1) * 80;
    int row0 = blockIdx.x * BM;
    int SW = Kp + 8;                    // A LDS row stride (ushorts)
    int ksteps = Kp >> 5;

    // ---- stage FULL-K A tile once: row ra=tid>>3, chunks c=(tid&7)+8i ----
    {
        int ra = tid >> 3;
        int gr = row0 + ra;
        const float* ar = A + (size_t)gr * K;
        for (int c = (tid & 7); c * 8 < Kp; c += 8) {
            int kb = c * 8;
            float vals[8];
            if (gr < M) {
                if (kb + 8 <= K) {
                    float4 f0 = *(const float4*)&ar[kb];
                    float4 f1 = *(const float4*)&ar[kb + 4];
                    vals[0]=f0.x; vals[1]=f0.y; vals[2]=f0.z; vals[3]=f0.w;
                    vals[4]=f1.x; vals[5]=f1.y; vals[6]=f1.z; vals[7]=f1.w;
                } else {
                    #pragma unroll
                    for (int i = 0; i < 8; i++)
                        vals[i] = (kb + i < K) ? ar[kb + i] : 0.f;
                }
                if (do_relu)
                    #pragma unroll
                    for (int i = 0; i < 8; i++) vals[i] = fmaxf(vals[i], 0.f);
            } else {
                #pragma unroll
                for (int i = 0; i < 8; i++) vals[i] = 0.f;
            }
            ushort8 hv;
            #pragma unroll
            for (int i = 0; i < 8; i++) hv[i] = f2bf_rne(vals[i]);
            *(ushort8*)&As[ra * SW + kb] = hv;
        }
    }

    for (int cb = 0; cb < NCB; cb++) {
        int col0 = cb * BN;
        f32x4 acc[5] = {};
        for (int ks = 0; ks < ksteps; ks++) {
            int k0 = ks << 5;
            __syncthreads();            // protect Bs (and As on first pass)
            // ---- stage B tile via async DMA: 640 tasks x 16B ----
            for (int t = tid; t < 640; t += 256) {
                int rb = t >> 2, ch = t & 3;
                __builtin_amdgcn_global_load_lds(
                    (const __attribute__((address_space(1))) unsigned int*)
                        &Bt[(size_t)(col0 + rb) * Kp + k0 + ch * 8],
                    (__attribute__((address_space(3))) unsigned int*)&Bs[t * 8],
                    16, 0, 0);
            }
            __syncthreads();            // compiler drains vmcnt before barrier
            short8 af, bf[5];
            af = *(const short8*)&As[(wr + ml) * SW + k0 + quad * 8];
            #pragma unroll
            for (int nt = 0; nt < 5; nt++)
                bf[nt] = *(const short8*)&Bs[(wc + nt * 16 + ml) * 32 + quad * 8];
            #pragma unroll
            for (int nt = 0; nt < 5; nt++)
                acc[nt] = __builtin_amdgcn_mfma_f32_16x16x32_bf16(af, bf[nt], acc[nt], 0, 0, 0);
        }
        // epilogue for this column block: bf16 store
        #pragma unroll
        for (int nt = 0; nt < 5; nt++) {
            #pragma unroll
            for (int r = 0; r < 4; r++) {
                int grow = row0 + wr + quad * 4 + r;
                if (grow < M)
                    xbh[(size_t)grow * OUTW + col0 + wc + nt * 16 + ml] =
                        f2bf_rne(acc[nt][r]);
            }
        }
    }
}

// ---- xbq[n,b] = xbh[n,b,:].q ; xbk likewise (reads bf16 xbh, coalesced) ----
__global__ __launch_bounds__(256) void qk3_kernel(
        const ushort_t* __restrict__ xbh, const float* __restrict__ q,
        const float* __restrict__ k, float* __restrict__ xbq,
        float* __restrict__ xbk) {
    __shared__ float sq[HID], sk[HID];
    int tid = threadIdx.x;
    if (tid < HID) { sq[tid] = q[tid]; sk[tid] = k[tid]; }
    __syncthreads();
    int idx = blockIdx.x * 256 + tid;     // idx = n*8 + b
    if (idx >= N_NODES * NB) return;
    const ushort_t* xr = xbh + (size_t)(idx >> 3) * OUTW + (idx & 7) * HID;
    float aq = 0.f, ak = 0.f;
    #pragma unroll
    for (int c = 0; c < 25; c++) {        // 25 x ushort4 (8B aligned)
        ushort4 v = *(const ushort4*)&xr[c * 4];
        #pragma unroll
        for (int i = 0; i < 4; i++) {
            float f = bf2f(((const ushort_t*)&v)[i]);
            aq = fmaf(f, sq[c * 4 + i], aq);
            ak = fmaf(f, sk[c * 4 + i], ak);
        }
    }
    xbq[idx] = aq;
    xbk[idx] = ak;
}

// ==== src-major, batched-4 Z rows; comp in LDS; keys via register window ====
// lane = eg*16 + c16; covers channels [8*c16, 8*c16+8) of edge p0+eg.
__global__ __launch_bounds__(256) void compute_z(
        const int* __restrict__ rowptr_s, const int* __restrict__ skey_s,
        const float* __restrict__ comp, const ushort_t* __restrict__ xbh,
        ushort_t* __restrict__ Z) {
    __shared__ float scomp[R_REL * NB];   // 1.6 KB
    int tid = threadIdx.x;
    for (int i = tid; i < R_REL * NB; i += 256) scomp[i] = comp[i];
    __syncthreads();
    int wave = tid >> 6, lane = tid & 63;
    int s = blockIdx.x * 4 + wave;
    if (s >= N_NODES) return;
    int beg = rowptr_s[s], end = rowptr_s[s + 1];
    if (beg == end) return;
    int eg = lane >> 4, c16 = lane & 15;
    int cbase = c16 * 8;
    float xr[NB][8];
    #pragma unroll
    for (int b = 0; b < NB; b++)
        #pragma unroll
        for (int i = 0; i < 8; i++) xr[b][i] = 0.f;
    if (cbase < HID) {
        #pragma unroll
        for (int b = 0; b < NB; b++) {
            const ushort_t* base = xbh + (size_t)s * OUTW + b * HID + cbase;
            ushort4 v0 = *(const ushort4*)base;       // 8B aligned
            xr[b][0] = bf2f(v0.x); xr[b][1] = bf2f(v0.y);
            xr[b][2] = bf2f(v0.z); xr[b][3] = bf2f(v0.w);
            if (cbase + 8 <= HID) {
                ushort4 v1 = *(const ushort4*)(base + 4);
                xr[b][4] = bf2f(v1.x); xr[b][5] = bf2f(v1.y);
                xr[b][6] = bf2f(v1.z); xr[b][7] = bf2f(v1.w);
            }
        }
    }
    for (int w0 = beg; w0 < end; w0 += 64) {
        // one coalesced key load covers the next 64 edges (16 quads)
        int kw = (w0 + lane < end) ? skey_s[w0 + lane] : 0;
        int wend = w0 + 64 < end ? w0 + 64 : end;
        for (int p0 = w0; p0 < wend; p0 += 4) {
            int j = p0 - w0 + eg;              // < 64 always
            int rt = __shfl(kw, j) & 63;       // zero memory ops in chain
            int p = p0 + eg;
            const float* cr = &scomp[rt * NB];
            float z[8] = {};
            #pragma unroll
            for (int b = 0; b < NB; b++) {
                float cb = cr[b];
                #pragma unroll
                for (int i = 0; i < 8; i++) z[i] = fmaf(cb, xr[b][i], z[i]);
            }
            ushort8 zz;
            #pragma unroll
            for (int i = 0; i < 8; i++) zz[i] = f2bf_rne(z[i]);
            if (p < end)
                *(ushort8*)&Z[(size_t)p * ZW + cbase] = zz;   // 16B, coalesced
        }
    }
}

// ==== dst-major: online softmax + paired-edge Z gather + bias; comp in LDS ====
__global__ __launch_bounds__(256) void msg_soft(
        const int* __restrict__ rowptr, const int* __restrict__ skey,
        const int* __restrict__ zidx,
        const float* __restrict__ comp, const ushort_t* __restrict__ Z,
        const float* __restrict__ xbq, const float* __restrict__ xbk,
        const float* __restrict__ bias, float* __restrict__ h) {
    __shared__ float scomp[R_REL * NB];   // 1.6 KB
    int tid = threadIdx.x;
    for (int i = tid; i < R_REL * NB; i += 256) scomp[i] = comp[i];
    __syncthreads();
    int wave = tid >> 6, lane = tid & 63;
    int d = blockIdx.x * 4 + wave;
    if (d >= N_NODES) return;
    int beg = rowptr[d], end = rowptr[d + 1];

    float4 qd0 = *(const float4*)&xbq[d * NB];
    float4 qd1 = *(const float4*)&xbq[d * NB + 4];

    int l5 = lane & 31;
    bool act = l5 < 25;
    int oc = l5 * 4;                  // channel base (4 channels per lane)
    f32x4 acc = {0.f, 0.f, 0.f, 0.f};
    float m = -1e30f, l = 0.f;

    for (int c0 = beg; c0 < end; c0 += 64) {
        int p = c0 + lane;
        bool valid = p < end;
        float a = -1e30f;
        int zi = 0;
        if (valid) {
            int key = skey[p];
            zi = zidx[p];
            int s = key >> 6, rt = key & 63;
            const float4 c0v = *(const float4*)&scomp[rt * NB];
            const float4 c1v = *(const float4*)&scomp[rt * NB + 4];
            const float4 k0v = *(const float4*)&xbk[s * NB];
            const float4 k1v = *(const float4*)&xbk[s * NB + 4];
            float qi = c0v.x*qd0.x + c0v.y*qd0.y + c0v.z*qd0.z + c0v.w*qd0.w
                     + c1v.x*qd1.x + c1v.y*qd1.y + c1v.z*qd1.z + c1v.w*qd1.w;
            float kj = c0v.x*k0v.x + c0v.y*k0v.y + c0v.z*k0v.z + c0v.w*k0v.w
                     + c1v.x*k1v.x + c1v.y*k1v.y + c1v.z*k1v.z + c1v.w*k1v.w;
            a = qi + kj;
            a = a > 0.f ? a : 0.2f * a;     // leaky_relu 0.2
        }
        float cm = a;
        #pragma unroll
        for (int off = 32; off; off >>= 1) cm = fmaxf(cm, __shfl_xor(cm, off));
        float M = fmaxf(m, cm);
        float scale = __expf(m - M);
        acc *= scale; l *= scale; m = M;
        float wgt = valid ? __expf(a - M) : 0.f;
        float cs = wgt;
        #pragma unroll
        for (int off = 32; off; off >>= 1) cs += __shfl_xor(cs, off);
        l += cs;
        int cnt = end - c0; if (cnt > 64) cnt = 64;
        for (int j = 0; j < cnt; j += 2) {
            int jj = j + (lane >> 5);         // even half: j, odd half: j+1
            float wj = __shfl(wgt, jj);       // invalid -> 0
            int   zj = __shfl(zi, jj);
            if (act) {
                ushort4 zz = *(const ushort4*)&Z[(size_t)zj * ZW + oc];
                acc.x = fmaf(wj, bf2f(zz.x), acc.x);
                acc.y = fmaf(wj, bf2f(zz.y), acc.y);
                acc.z = fmaf(wj, bf2f(zz.z), acc.z);
                acc.w = fmaf(wj, bf2f(zz.w), acc.w);
            }
        }
    }
    // combine even/odd-edge halves: lane ℓ (<25) += lane ℓ+32
    #pragma unroll
    for (int i = 0; i < 4; i++) acc[i] += __shfl_xor(acc[i], 32);
    if (lane < 25) {
        float inv = 1.f / (l + 1e-16f);
        float4 r;
        r.x = bias[oc]     + acc.x * inv;
        r.y = bias[oc + 1] + acc.y * inv;
        r.z = bias[oc + 2] + acc.z * inv;
        r.w = bias[oc + 3] + acc.w * inv;
        *(float4*)&h[(size_t)d * HID + oc] = r;   // 16B aligned (400|16)
    }
}

// ---- pooled = mean(relu(h2[qidx])); out = pooled @ Wl^T + bl ----
__global__ __launch_bounds__(128) void head_kernel(
        const float* __restrict__ h2, const int* __restrict__ qidx,
        const float* __restrict__ Wl, const float* __restrict__ bl,
        float* __restrict__ out) {
    __shared__ float pooled[HID];
    int tid = threadIdx.x;
    if (tid < HID) {
        float s = 0.f;
        for (int i = 0; i < NQ; i++)
            s += fmaxf(h2[(size_t)qidx[i] * HID + tid], 0.f);
        pooled[tid] = s * (1.0f / NQ);
    }
    __syncthreads();
    if (tid < CLS) {
        float s = bl[tid];
        for (int o = 0; o < HID; o++) s = fmaf(pooled[o], Wl[tid * HID + o], s);
        out[tid] = s;
    }
}

extern "C" void kernel_launch(void* const* d_in, const int* in_sizes, int n_in,
                              void* d_out, int out_size, void* d_ws, size_t ws_size,
                              hipStream_t stream) {
    const float* x      = (const float*)d_in[0];
    const int*   ei     = (const int*)  d_in[1];
    const int*   et     = (const int*)  d_in[2];
    const int*   qidx   = (const int*)  d_in[3];
    const float* comp1  = (const float*)d_in[4];
    const float* basis1 = (const float*)d_in[5];
    const float* q1     = (const float*)d_in[6];
    const float* k1     = (const float*)d_in[7];
    const float* b1     = (const float*)d_in[8];
    const float* comp2  = (const float*)d_in[9];
    const float* basis2 = (const float*)d_in[10];
    const float* q2     = (const float*)d_in[11];
    const float* k2     = (const float*)d_in[12];
    const float* b2     = (const float*)d_in[13];
    const float* Wl     = (const float*)d_in[14];
    const float* bl     = (const float*)d_in[15];
    float* out = (float*)d_out;

    char* w = (char*)d_ws;
    size_t off = 0;
    auto alloc = [&](size_t nbytes) {
        void* p = (void*)(w + off);
        off += ((nbytes + 255) / 256) * 256;
        return p;
    };
    ushort_t* xbh    = (ushort_t*)alloc((size_t)N_NODES * OUTW * 2); // 32 MB
    ushort_t* Z      = (ushort_t*)alloc((size_t)E_EDGES * ZW * 2);   // 82 MB
    float*    h1     = (float*)alloc((size_t)N_NODES * HID * 4);     // 8 MB
    float*    h2     = (float*)alloc((size_t)N_NODES * HID * 4);     // 8 MB
    ushort_t* Bt1    = (ushort_t*)alloc((size_t)OUTW * KP1 * 2);     // 512 KB
    ushort_t* Bt2    = (ushort_t*)alloc((size_t)OUTW * KP2 * 2);     // 205 KB
    float*    xbq    = (float*)alloc((size_t)N_NODES * NB * 4);
    float*    xbk    = (float*)alloc((size_t)N_NODES * NB * 4);
    int*      deg_d  = (int*)alloc(N_NODES * 4);
    int*      deg_s  = (int*)alloc(N_NODES * 4);
    int*      rp_d   = (int*)alloc((N_NODES + 1) * 4);
    int*      rp_s   = (int*)alloc((N_NODES + 1) * 4);
    int*      cur_d  = (int*)alloc(N_NODES * 4);
    int*      cur_s  = (int*)alloc(N_NODES * 4);
    int*      bsum_d = (int*)alloc(SCAN_BLKS * 4);
    int*      bsum_s = (int*)alloc(SCAN_BLKS * 4);
    int*      skey   = (int*)alloc(E_EDGES * 4);
    int*      skey_s = (int*)alloc(E_EDGES * 4);
    int*      zidx   = (int*)alloc(E_EDGES * 4);

    // ---- CSR build (once; same graph both layers) + both Bt upfront ----
    zero_deg2<<<SCAN_BLKS, 256, 0, stream>>>(deg_d, deg_s);
    hist2_kernel<<<(E_EDGES + 255) / 256, 256, 0, stream>>>(ei, deg_d, deg_s);
    scan1_both<<<2 * SCAN_BLKS, 256, 0, stream>>>(deg_d, rp_d, bsum_d, deg_s, rp_s, bsum_s);
    scan2_both<<<2, 128, 0, stream>>>(bsum_d, rp_d, bsum_s, rp_s);
    scan3_both<<<2 * SCAN_BLKS, 256, 0, stream>>>(rp_d, bsum_d, cur_d, rp_s, bsum_s, cur_s);
    scatter_both<<<(E_EDGES + 255) / 256, 256, 0, stream>>>(ei, et, cur_d, cur_s, skey, skey_s, zidx);
    split_bt_both<<<(OUTW * (KP1 + KP2) + 255) / 256, 256, 0, stream>>>(basis1, Bt1, basis2, Bt2);

    auto layer = [&](const float* input, int K, int Kp, int relu_in,
                     const ushort_t* Bt, const float* comp, const float* q,
                     const float* k, const float* bias, float* hout) {
        gemm_mfma<<<(N_NODES + BM - 1) / BM, 256, 0, stream>>>(input, Bt, xbh, N_NODES, K, Kp, relu_in);
        qk3_kernel<<<(N_NODES * NB + 255) / 256, 256, 0, stream>>>(xbh, q, k, xbq, xbk);
        compute_z<<<(N_NODES + 3) / 4, 256, 0, stream>>>(rp_s, skey_s, comp, xbh, Z);
        msg_soft<<<(N_NODES + 3) / 4, 256, 0, stream>>>(rp_d, skey, zidx, comp, Z, xbq, xbk, bias, hout);
    };

    layer(x,  IN_CH, KP1, 0, Bt1, comp1, q1, k1, b1, h1);
    layer(h1, HID,   KP2, 1, Bt2, comp2, q2, k2, b2, h2);
    head_kernel<<<1, 128, 0, stream>>>(h2, qidx, Wl, bl, out);
}

// Round 17
// 366.258 us; speedup vs baseline: 1.1162x; 1.0007x over previous
//
#include <hip/hip_runtime.h>
#include <math.h>

#define N_NODES 20000
#define E_EDGES 320000
#define IN_CH   300
#define HID     100
#define R_REL   50
#define NB      8
#define CLS     3
#define NQ      64
#define OUTW    800   // NB * HID
#define ZW      128   // Z row stride (ushorts): 256-B rows, batched-4 writes
#define KP1     320
#define KP2     128
#define SCAN_BLKS ((N_NODES + 255) / 256)   // 79

typedef unsigned short ushort_t;
typedef __attribute__((ext_vector_type(8))) short     short8;
typedef __attribute__((ext_vector_type(8))) unsigned short ushort8;
typedef __attribute__((ext_vector_type(4))) float     f32x4;
typedef __attribute__((ext_vector_type(2))) float     f32x2;

__device__ __forceinline__ ushort_t f2bf_rne(float f) {   // round-nearest-even
    unsigned u = __float_as_uint(f);
    unsigned r = (u + 0x7fffu + ((u >> 16) & 1u)) >> 16;
    return (ushort_t)r;
}
__device__ __forceinline__ float bf2f(ushort_t u) {
    return __uint_as_float((unsigned)u << 16);
}

// ============================ CSR build =================================
__global__ __launch_bounds__(256) void zero_deg2(int* __restrict__ dd,
                                                 int* __restrict__ ds) {
    int i = blockIdx.x * 256 + threadIdx.x;
    if (i < N_NODES) { dd[i] = 0; ds[i] = 0; }
}

__global__ __launch_bounds__(256) void hist2_kernel(
        const int* __restrict__ ei, int* __restrict__ dd,
        int* __restrict__ ds) {
    int e = blockIdx.x * 256 + threadIdx.x;
    if (e < E_EDGES) {
        atomicAdd(&dd[ei[E_EDGES + e]], 1);
        atomicAdd(&ds[ei[e]], 1);
    }
}

// dual-set scans: blockIdx selects (deg_d...) or (deg_s...) set
__global__ __launch_bounds__(256) void scan1_both(
        const int* __restrict__ deg_d, int* __restrict__ rp_d, int* __restrict__ bsum_d,
        const int* __restrict__ deg_s, int* __restrict__ rp_s, int* __restrict__ bsum_s) {
    int set = blockIdx.x / SCAN_BLKS, blk = blockIdx.x % SCAN_BLKS;
    const int* deg = set ? deg_s : deg_d;
    int* rowptr    = set ? rp_s  : rp_d;
    int* bsum      = set ? bsum_s : bsum_d;
    __shared__ int s[256];
    int tid = threadIdx.x;
    int idx = blk * 256 + tid;
    int v = (idx < N_NODES) ? deg[idx] : 0;
    s[tid] = v; __syncthreads();
    #pragma unroll
    for (int off = 1; off < 256; off <<= 1) {
        int t = (tid >= off) ? s[tid - off] : 0;
        __syncthreads();
        s[tid] += t;
        __syncthreads();
    }
    if (idx < N_NODES) rowptr[idx] = s[tid] - v;   // exclusive
    if (tid == 255) bsum[blk] = s[255];
}

__global__ __launch_bounds__(128) void scan2_both(
        int* __restrict__ bsum_d, int* __restrict__ rp_d,
        int* __restrict__ bsum_s, int* __restrict__ rp_s) {
    int* bsum   = blockIdx.x ? bsum_s : bsum_d;
    int* rowptr = blockIdx.x ? rp_s   : rp_d;
    __shared__ int s[128];
    int tid = threadIdx.x;
    int v = (tid < SCAN_BLKS) ? bsum[tid] : 0;
    s[tid] = v; __syncthreads();
    #pragma unroll
    for (int off = 1; off < 128; off <<= 1) {
        int t = (tid >= off) ? s[tid - off] : 0;
        __syncthreads();
        s[tid] += t;
        __syncthreads();
    }
    if (tid < SCAN_BLKS) bsum[tid] = s[tid] - v;   // exclusive
    if (tid == 0) rowptr[N_NODES] = E_EDGES;
}

__global__ __launch_bounds__(256) void scan3_both(
        int* __restrict__ rp_d, const int* __restrict__ bsum_d, int* __restrict__ cur_d,
        int* __restrict__ rp_s, const int* __restrict__ bsum_s, int* __restrict__ cur_s) {
    int set = blockIdx.x / SCAN_BLKS, blk = blockIdx.x % SCAN_BLKS;
    int* rowptr      = set ? rp_s   : rp_d;
    const int* bsum  = set ? bsum_s : bsum_d;
    int* cursor      = set ? cur_s  : cur_d;
    int idx = blk * 256 + threadIdx.x;
    if (idx < N_NODES) {
        int v = rowptr[idx] + bsum[blk];
        rowptr[idx] = v;
        cursor[idx] = v;
    }
}

// fused scatter: dst-CSR key (src,rel), src-CSR key (rel), and zidx map
__global__ __launch_bounds__(256) void scatter_both(
        const int* __restrict__ ei, const int* __restrict__ et,
        int* __restrict__ cur_d, int* __restrict__ cur_s,
        int* __restrict__ skey, int* __restrict__ skey_s,
        int* __restrict__ zidx) {
    int e = blockIdx.x * 256 + threadIdx.x;
    if (e >= E_EDGES) return;
    int s = ei[e], d = ei[E_EDGES + e], rt = et[e];
    int p = atomicAdd(&cur_d[d], 1);
    skey[p] = (s << 6) | rt;                 // dst-order: (src, rel)
    int qp = atomicAdd(&cur_s[s], 1);
    skey_s[qp] = rt;                         // src-order: rel only
    zidx[p] = qp;                            // dst-slot -> Z row (src-slot)
}

// ---- both layers' basis -> Bt (transposed bf16, zero-padded), one dispatch ----
__global__ __launch_bounds__(256) void split_bt_both(
        const float* __restrict__ basis1, ushort_t* __restrict__ Bt1,
        const float* __restrict__ basis2, ushort_t* __restrict__ Bt2) {
    int idx = blockIdx.x * 256 + threadIdx.x;
    const int n1 = OUTW * KP1;
    if (idx < n1) {
        int n = idx / KP1, k = idx - n * KP1;
        int b = n / HID, o = n - b * HID;
        float v = (k < IN_CH) ? basis1[((size_t)b * IN_CH + k) * HID + o] : 0.f;
        Bt1[idx] = f2bf_rne(v);
    } else {
        int i2 = idx - n1;
        if (i2 >= OUTW * KP2) return;
        int n = i2 / KP2, k = i2 - n * KP2;
        int b = n / HID, o = n - b * HID;
        float v = (k < HID) ? basis2[((size_t)b * HID + k) * HID + o] : 0.f;
        Bt2[i2] = f2bf_rne(v);
    }
}

// ---- MFMA GEMM: xbh[M,800](bf16) = A[M,K] * B[K,800] ----
// BM=16 x 128-thread blocks: grid 1250 -> ~4.9 blocks/CU (2x overlap vs
// BM=32). Full-K A tile staged once; B per K-step via block-wide DMA;
// column blocks looped inside. A total stage work unchanged; Bt stays L2-hot.
#define BM 16
#define BN 160
#define NCB (OUTW / BN)   // 5
__global__ __launch_bounds__(128) void gemm_mfma(
        const float* __restrict__ A, const ushort_t* __restrict__ Bt,
        ushort_t* __restrict__ xbh, int M, int K, int Kp, int do_relu) {
    __shared__ ushort_t As[BM * 328];   // max Kp=320 -> stride 328 (10.5 KB)
    __shared__ ushort_t Bs[BN * 32];    // 10 KB
    int tid  = threadIdx.x;
    int lane = tid & 63, wave = tid >> 6;     // 2 waves
    int ml = lane & 15, quad = lane >> 4;
    int wc = wave * 80;                 // wave 0: cols 0-79, wave 1: 80-159
    int row0 = blockIdx.x * BM;
    int SW = Kp + 8;                    // A LDS row stride (ushorts)
    int ksteps = Kp >> 5;

    // ---- stage FULL-K A tile once: row ra=tid>>3, chunks c=(tid&7)+8i ----
    {
        int ra = tid >> 3;              // 16 rows, 8 threads each
        int gr = row0 + ra;
        const float* ar = A + (size_t)gr * K;
        for (int c = (tid & 7); c * 8 < Kp; c += 8) {
            int kb = c * 8;
            float vals[8];
            if (gr < M) {
                if (kb + 8 <= K) {
                    float4 f0 = *(const float4*)&ar[kb];
                    float4 f1 = *(const float4*)&ar[kb + 4];
                    vals[0]=f0.x; vals[1]=f0.y; vals[2]=f0.z; vals[3]=f0.w;
                    vals[4]=f1.x; vals[5]=f1.y; vals[6]=f1.z; vals[7]=f1.w;
                } else {
                    #pragma unroll
                    for (int i = 0; i < 8; i++)
                        vals[i] = (kb + i < K) ? ar[kb + i] : 0.f;
                }
                if (do_relu)
                    #pragma unroll
                    for (int i = 0; i < 8; i++) vals[i] = fmaxf(vals[i], 0.f);
            } else {
                #pragma unroll
                for (int i = 0; i < 8; i++) vals[i] = 0.f;
            }
            ushort8 hv;
            #pragma unroll
            for (int i = 0; i < 8; i++) hv[i] = f2bf_rne(vals[i]);
            *(ushort8*)&As[ra * SW + kb] = hv;
        }
    }

    for (int cb = 0; cb < NCB; cb++) {
        int col0 = cb * BN;
        f32x4 acc[5] = {};
        for (int ks = 0; ks < ksteps; ks++) {
            int k0 = ks << 5;
            __syncthreads();            // protect Bs (and As on first pass)
            // ---- stage B tile via async DMA: 640 tasks x 16B, 5/thread ----
            for (int t = tid; t < 640; t += 128) {
                int rb = t >> 2, ch = t & 3;
                __builtin_amdgcn_global_load_lds(
                    (const __attribute__((address_space(1))) unsigned int*)
                        &Bt[(size_t)(col0 + rb) * Kp + k0 + ch * 8],
                    (__attribute__((address_space(3))) unsigned int*)&Bs[t * 8],
                    16, 0, 0);
            }
            __syncthreads();            // compiler drains vmcnt before barrier
            short8 af, bf[5];
            af = *(const short8*)&As[ml * SW + k0 + quad * 8];
            #pragma unroll
            for (int nt = 0; nt < 5; nt++)
                bf[nt] = *(const short8*)&Bs[(wc + nt * 16 + ml) * 32 + quad * 8];
            #pragma unroll
            for (int nt = 0; nt < 5; nt++)
                acc[nt] = __builtin_amdgcn_mfma_f32_16x16x32_bf16(af, bf[nt], acc[nt], 0, 0, 0);
        }
        // epilogue for this column block: bf16 store
        #pragma unroll
        for (int nt = 0; nt < 5; nt++) {
            #pragma unroll
            for (int r = 0; r < 4; r++) {
                int grow = row0 + quad * 4 + r;
                if (grow < M)
                    xbh[(size_t)grow * OUTW + col0 + wc + nt * 16 + ml] =
                        f2bf_rne(acc[nt][r]);
            }
        }
    }
}

// ---- xbq[n,b] = xbh[n,b,:].q ; xbk likewise (reads bf16 xbh, coalesced) ----
__global__ __launch_bounds__(256) void qk3_kernel(
        const ushort_t* __restrict__ xbh, const float* __restrict__ q,
        const float* __restrict__ k, float* __restrict__ xbq,
        float* __restrict__ xbk) {
    __shared__ float sq[HID], sk[HID];
    int tid = threadIdx.x;
    if (tid < HID) { sq[tid] = q[tid]; sk[tid] = k[tid]; }
    __syncthreads();
    int idx = blockIdx.x * 256 + tid;     // idx = n*8 + b
    if (idx >= N_NODES * NB) return;
    const ushort_t* xr = xbh + (size_t)(idx >> 3) * OUTW + (idx & 7) * HID;
    float aq = 0.f, ak = 0.f;
    #pragma unroll
    for (int c = 0; c < 25; c++) {        // 25 x ushort4 (8B aligned)
        ushort4 v = *(const ushort4*)&xr[c * 4];
        #pragma unroll
        for (int i = 0; i < 4; i++) {
            float f = bf2f(((const ushort_t*)&v)[i]);
            aq = fmaf(f, sq[c * 4 + i], aq);
            ak = fmaf(f, sk[c * 4 + i], ak);
        }
    }
    xbq[idx] = aq;
    xbk[idx] = ak;
}

// ==== src-major, batched-4 Z rows; comp in LDS; keys via register window ====
// lane = eg*16 + c16; covers channels [8*c16, 8*c16+8) of edge p0+eg.
__global__ __launch_bounds__(256) void compute_z(
        const int* __restrict__ rowptr_s, const int* __restrict__ skey_s,
        const float* __restrict__ comp, const ushort_t* __restrict__ xbh,
        ushort_t* __restrict__ Z) {
    __shared__ float scomp[R_REL * NB];   // 1.6 KB
    int tid = threadIdx.x;
    for (int i = tid; i < R_REL * NB; i += 256) scomp[i] = comp[i];
    __syncthreads();
    int wave = tid >> 6, lane = tid & 63;
    int s = blockIdx.x * 4 + wave;
    if (s >= N_NODES) return;
    int beg = rowptr_s[s], end = rowptr_s[s + 1];
    if (beg == end) return;
    int eg = lane >> 4, c16 = lane & 15;
    int cbase = c16 * 8;
    float xr[NB][8];
    #pragma unroll
    for (int b = 0; b < NB; b++)
        #pragma unroll
        for (int i = 0; i < 8; i++) xr[b][i] = 0.f;
    if (cbase < HID) {
        #pragma unroll
        for (int b = 0; b < NB; b++) {
            const ushort_t* base = xbh + (size_t)s * OUTW + b * HID + cbase;
            ushort4 v0 = *(const ushort4*)base;       // 8B aligned
            xr[b][0] = bf2f(v0.x); xr[b][1] = bf2f(v0.y);
            xr[b][2] = bf2f(v0.z); xr[b][3] = bf2f(v0.w);
            if (cbase + 8 <= HID) {
                ushort4 v1 = *(const ushort4*)(base + 4);
                xr[b][4] = bf2f(v1.x); xr[b][5] = bf2f(v1.y);
                xr[b][6] = bf2f(v1.z); xr[b][7] = bf2f(v1.w);
            }
        }
    }
    for (int w0 = beg; w0 < end; w0 += 64) {
        // one coalesced key load covers the next 64 edges (16 quads)
        int kw = (w0 + lane < end) ? skey_s[w0 + lane] : 0;
        int wend = w0 + 64 < end ? w0 + 64 : end;
        for (int p0 = w0; p0 < wend; p0 += 4) {
            int j = p0 - w0 + eg;              // < 64 always
            int rt = __shfl(kw, j) & 63;       // zero memory ops in chain
            int p = p0 + eg;
            const float* cr = &scomp[rt * NB];
            float z[8] = {};
            #pragma unroll
            for (int b = 0; b < NB; b++) {
                float cb = cr[b];
                #pragma unroll
                for (int i = 0; i < 8; i++) z[i] = fmaf(cb, xr[b][i], z[i]);
            }
            ushort8 zz;
            #pragma unroll
            for (int i = 0; i < 8; i++) zz[i] = f2bf_rne(z[i]);
            if (p < end)
                *(ushort8*)&Z[(size_t)p * ZW + cbase] = zz;   // 16B, coalesced
        }
    }
}

// ==== dst-major: online softmax + paired-edge Z gather + bias; comp in LDS ====
__global__ __launch_bounds__(256) void msg_soft(
        const int* __restrict__ rowptr, const int* __restrict__ skey,
        const int* __restrict__ zidx,
        const float* __restrict__ comp, const ushort_t* __restrict__ Z,
        const float* __restrict__ xbq, const float* __restrict__ xbk,
        const float* __restrict__ bias, float* __restrict__ h) {
    __shared__ float scomp[R_REL * NB];   // 1.6 KB
    int tid = threadIdx.x;
    for (int i = tid; i < R_REL * NB; i += 256) scomp[i] = comp[i];
    __syncthreads();
    int wave = tid >> 6, lane = tid & 63;
    int d = blockIdx.x * 4 + wave;
    if (d >= N_NODES) return;
    int beg = rowptr[d], end = rowptr[d + 1];

    float4 qd0 = *(const float4*)&xbq[d * NB];
    float4 qd1 = *(const float4*)&xbq[d * NB + 4];

    int l5 = lane & 31;
    bool act = l5 < 25;
    int oc = l5 * 4;                  // channel base (4 channels per lane)
    f32x4 acc = {0.f, 0.f, 0.f, 0.f};
    float m = -1e30f, l = 0.f;

    for (int c0 = beg; c0 < end; c0 += 64) {
        int p = c0 + lane;
        bool valid = p < end;
        float a = -1e30f;
        int zi = 0;
        if (valid) {
            int key = skey[p];
            zi = zidx[p];
            int s = key >> 6, rt = key & 63;
            const float4 c0v = *(const float4*)&scomp[rt * NB];
            const float4 c1v = *(const float4*)&scomp[rt * NB + 4];
            const float4 k0v = *(const float4*)&xbk[s * NB];
            const float4 k1v = *(const float4*)&xbk[s * NB + 4];
            float qi = c0v.x*qd0.x + c0v.y*qd0.y + c0v.z*qd0.z + c0v.w*qd0.w
                     + c1v.x*qd1.x + c1v.y*qd1.y + c1v.z*qd1.z + c1v.w*qd1.w;
            float kj = c0v.x*k0v.x + c0v.y*k0v.y + c0v.z*k0v.z + c0v.w*k0v.w
                     + c1v.x*k1v.x + c1v.y*k1v.y + c1v.z*k1v.z + c1v.w*k1v.w;
            a = qi + kj;
            a = a > 0.f ? a : 0.2f * a;     // leaky_relu 0.2
        }
        float cm = a;
        #pragma unroll
        for (int off = 32; off; off >>= 1) cm = fmaxf(cm, __shfl_xor(cm, off));
        float M = fmaxf(m, cm);
        float scale = __expf(m - M);
        acc *= scale; l *= scale; m = M;
        float wgt = valid ? __expf(a - M) : 0.f;
        float cs = wgt;
        #pragma unroll
        for (int off = 32; off; off >>= 1) cs += __shfl_xor(cs, off);
        l += cs;
        int cnt = end - c0; if (cnt > 64) cnt = 64;
        for (int j = 0; j < cnt; j += 2) {
            int jj = j + (lane >> 5);         // even half: j, odd half: j+1
            float wj = __shfl(wgt, jj);       // invalid -> 0
            int   zj = __shfl(zi, jj);
            if (act) {
                ushort4 zz = *(const ushort4*)&Z[(size_t)zj * ZW + oc];
                acc.x = fmaf(wj, bf2f(zz.x), acc.x);
                acc.y = fmaf(wj, bf2f(zz.y), acc.y);
                acc.z = fmaf(wj, bf2f(zz.z), acc.z);
                acc.w = fmaf(wj, bf2f(zz.w), acc.w);
            }
        }
    }
    // combine even/odd-edge halves: lane ℓ (<25) += lane ℓ+32
    #pragma unroll
    for (int i = 0; i < 4; i++) acc[i] += __shfl_xor(acc[i], 32);
    if (lane < 25) {
        float inv = 1.f / (l + 1e-16f);
        float4 r;
        r.x = bias[oc]     + acc.x * inv;
        r.y = bias[oc + 1] + acc.y * inv;
        r.z = bias[oc + 2] + acc.z * inv;
        r.w = bias[oc + 3] + acc.w * inv;
        *(float4*)&h[(size_t)d * HID + oc] = r;   // 16B aligned (400|16)
    }
}

// ---- pooled = mean(relu(h2[qidx])); out = pooled @ Wl^T + bl ----
__global__ __launch_bounds__(128) void head_kernel(
        const float* __restrict__ h2, const int* __restrict__ qidx,
        const float* __restrict__ Wl, const float* __restrict__ bl,
        float* __restrict__ out) {
    __shared__ float pooled[HID];
    int tid = threadIdx.x;
    if (tid < HID) {
        float s = 0.f;
        for (int i = 0; i < NQ; i++)
            s += fmaxf(h2[(size_t)qidx[i] * HID + tid], 0.f);
        pooled[tid] = s * (1.0f / NQ);
    }
    __syncthreads();
    if (tid < CLS) {
        float s = bl[tid];
        for (int o = 0; o < HID; o++) s = fmaf(pooled[o], Wl[tid * HID + o], s);
        out[tid] = s;
    }
}

extern "C" void kernel_launch(void* const* d_in, const int* in_sizes, int n_in,
                              void* d_out, int out_size, void* d_ws, size_t ws_size,
                              hipStream_t stream) {
    const float* x      = (const float*)d_in[0];
    const int*   ei     = (const int*)  d_in[1];
    const int*   et     = (const int*)  d_in[2];
    const int*   qidx   = (const int*)  d_in[3];
    const float* comp1  = (const float*)d_in[4];
    const float* basis1 = (const float*)d_in[5];
    const float* q1     = (const float*)d_in[6];
    const float* k1     = (const float*)d_in[7];
    const float* b1     = (const float*)d_in[8];
    const float* comp2  = (const float*)d_in[9];
    const float* basis2 = (const float*)d_in[10];
    const float* q2     = (const float*)d_in[11];
    const float* k2     = (const float*)d_in[12];
    const float* b2     = (const float*)d_in[13];
    const float* Wl     = (const float*)d_in[14];
    const float* bl     = (const float*)d_in[15];
    float* out = (float*)d_out;

    char* w = (char*)d_ws;
    size_t off = 0;
    auto alloc = [&](size_t nbytes) {
        void* p = (void*)(w + off);
        off += ((nbytes + 255) / 256) * 256;
        return p;
    };
    ushort_t* xbh    = (ushort_t*)alloc((size_t)N_NODES * OUTW * 2); // 32 MB
    ushort_t* Z      = (ushort_t*)alloc((size_t)E_EDGES * ZW * 2);   // 82 MB
    float*    h1     = (float*)alloc((size_t)N_NODES * HID * 4);     // 8 MB
    float*    h2     = (float*)alloc((size_t)N_NODES * HID * 4);     // 8 MB
    ushort_t* Bt1    = (ushort_t*)alloc((size_t)OUTW * KP1 * 2);     // 512 KB
    ushort_t* Bt2    = (ushort_t*)alloc((size_t)OUTW * KP2 * 2);     // 205 KB
    float*    xbq    = (float*)alloc((size_t)N_NODES * NB * 4);
    float*    xbk    = (float*)alloc((size_t)N_NODES * NB * 4);
    int*      deg_d  = (int*)alloc(N_NODES * 4);
    int*      deg_s  = (int*)alloc(N_NODES * 4);
    int*      rp_d   = (int*)alloc((N_NODES + 1) * 4);
    int*      rp_s   = (int*)alloc((N_NODES + 1) * 4);
    int*      cur_d  = (int*)alloc(N_NODES * 4);
    int*      cur_s  = (int*)alloc(N_NODES * 4);
    int*      bsum_d = (int*)alloc(SCAN_BLKS * 4);
    int*      bsum_s = (int*)alloc(SCAN_BLKS * 4);
    int*      skey   = (int*)alloc(E_EDGES * 4);
    int*      skey_s = (int*)alloc(E_EDGES * 4);
    int*      zidx   = (int*)alloc(E_EDGES * 4);

    // ---- CSR build (once; same graph both layers) + both Bt upfront ----
    zero_deg2<<<SCAN_BLKS, 256, 0, stream>>>(deg_d, deg_s);
    hist2_kernel<<<(E_EDGES + 255) / 256, 256, 0, stream>>>(ei, deg_d, deg_s);
    scan1_both<<<2 * SCAN_BLKS, 256, 0, stream>>>(deg_d, rp_d, bsum_d, deg_s, rp_s, bsum_s);
    scan2_both<<<2, 128, 0, stream>>>(bsum_d, rp_d, bsum_s, rp_s);
    scan3_both<<<2 * SCAN_BLKS, 256, 0, stream>>>(rp_d, bsum_d, cur_d, rp_s, bsum_s, cur_s);
    scatter_both<<<(E_EDGES + 255) / 256, 256, 0, stream>>>(ei, et, cur_d, cur_s, skey, skey_s, zidx);
    split_bt_both<<<(OUTW * (KP1 + KP2) + 255) / 256, 256, 0, stream>>>(basis1, Bt1, basis2, Bt2);

    auto layer = [&](const float* input, int K, int Kp, int relu_in,
                     const ushort_t* Bt, const float* comp, const float* q,
                     const float* k, const float* bias, float* hout) {
        gemm_mfma<<<(N_NODES + BM - 1) / BM, 128, 0, stream>>>(input, Bt, xbh, N_NODES, K, Kp, relu_in);
        qk3_kernel<<<(N_NODES * NB + 255) / 256, 256, 0, stream>>>(xbh, q, k, xbq, xbk);
        compute_z<<<(N_NODES + 3) / 4, 256, 0, stream>>>(rp_s, skey_s, comp, xbh, Z);
        msg_soft<<<(N_NODES + 3) / 4, 256, 0, stream>>>(rp_d, skey, zidx, comp, Z, xbq, xbk, bias, hout);
    };

    layer(x,  IN_CH, KP1, 0, Bt1, comp1, q1, k1, b1, h1);
    layer(h1, HID,   KP2, 1, Bt2, comp2, q2, k2, b2, h2);
    head_kernel<<<1, 128, 0, stream>>>(h2, qidx, Wl, bl, out);
}